// Round 3
// baseline (319.422 us; speedup 1.0000x reference)
//
#include <hip/hip_runtime.h>

#define NB 4096
#define MM 64
#define DD 256
#define LN_EPS 1e-5f

// ws layout (floats):
//   [0,            512*DD)    wcat : [wt^T ; wh^T]  (512 rows x 256)
//   [WS_HW,  +NB*DD)          hW
//   [WS_CTX, +2*NB*DD)        ctx  (row = side*NB + b)
#define WS_WCAT 0
#define WS_HW   (512 * DD)
#define WS_CTX  (WS_HW + NB * DD)

// ---------------- T: transpose wt, wh into wcat ----------------
__global__ __launch_bounds__(256)
void k_transpose(const float* __restrict__ wt, const float* __restrict__ wh,
                 float* __restrict__ wcat)
{
    const int mat   = blockIdx.x >> 4;
    const int tile  = blockIdx.x & 15;
    const int dBase = (tile >> 2) * 64;
    const int kBase = (tile & 3) * 64;
    const float* __restrict__ w = mat ? wh : wt;

    __shared__ float tile_s[64][65];
    const int c  = threadIdx.x & 63;
    const int rr = threadIdx.x >> 6;

    #pragma unroll
    for (int r = rr; r < 64; r += 4)
        tile_s[r][c] = w[(dBase + r) * DD + kBase + c];
    __syncthreads();
    #pragma unroll
    for (int kr = rr; kr < 64; kr += 4)
        wcat[(mat * 256 + kBase + kr) * DD + dBase + c] = tile_s[c][kr];
}

// ---------------- A: hW[b,:] = (head_right-head_left)[b,:] @ bw ----------------
__global__ __launch_bounds__(256)
void k_bilinear(const float* __restrict__ head_left,
                const float* __restrict__ head_right,
                const float* __restrict__ bw,
                float* __restrict__ hW)
{
    const int blk  = blockIdx.x;          // 256 blocks x 16 rows
    const int t    = threadIdx.x;
    const int lane = t & 63;
    const int w    = t >> 6;

    __shared__ float weak_s[16][DD];
    #pragma unroll
    for (int r = 0; r < 16; ++r) {
        const size_t idx = (size_t)(blk * 16 + r) * DD + t;
        weak_s[r][t] = head_right[idx] - head_left[idx];
    }
    __syncthreads();

    float4 acc[4];
    #pragma unroll
    for (int r = 0; r < 4; ++r) acc[r] = make_float4(0.f, 0.f, 0.f, 0.f);

    for (int k = 0; k < DD; ++k) {
        const float4 w4 = *(const float4*)(bw + k * DD + 4 * lane);
        #pragma unroll
        for (int r = 0; r < 4; ++r) {
            const float x = weak_s[4 * w + r][k];
            acc[r].x += x * w4.x; acc[r].y += x * w4.y;
            acc[r].z += x * w4.z; acc[r].w += x * w4.w;
        }
    }
    #pragma unroll
    for (int r = 0; r < 4; ++r)
        *(float4*)(hW + (size_t)(blk * 16 + 4 * w + r) * DD + 4 * lane) = acc[r];
}

// ---------------- attn: ONE WAVE per (b,side). No barriers. ----------------
__global__ __launch_bounds__(256, 4)
void k_attn(const float* __restrict__ rel_left,
            const float* __restrict__ tail_left,
            const float* __restrict__ rel_right,
            const float* __restrict__ tail_right,
            const unsigned char* __restrict__ mask_left,
            const unsigned char* __restrict__ mask_right,
            const float* __restrict__ hW,
            float* __restrict__ ctx)
{
    const int t    = threadIdx.x;
    const int lane = t & 63;
    const int pair = t >> 6;                       // 4 pairs per block
    const int pid  = blockIdx.x * 4 + pair;        // 8192 pairs
    const int b    = pid >> 1;
    const int side = pid & 1;

    const float* __restrict__ rel  = side ? rel_right  : rel_left;
    const float* __restrict__ tail = side ? tail_right : tail_left;
    const unsigned char* __restrict__ mask = side ? mask_right : mask_left;

    __shared__ float att_s[4][MM];                 // wave-local only

    const float4 hw4 = *(const float4*)(hW + (size_t)b * DD + 4 * lane);

    // ---- scores in two batches of 32 m's; batched butterfly reduce ----
    float sc[2];                                   // sc[h] = score[h*32 + (lane&31)]
    #pragma unroll
    for (int h = 0; h < 2; ++h) {
        float A[32];
        #pragma unroll 8
        for (int j = 0; j < 32; ++j) {
            const float4 r4 = *(const float4*)(rel + ((size_t)(b * MM + h * 32 + j)) * DD + 4 * lane);
            A[j] = hw4.x * r4.x + hw4.y * r4.y + hw4.z * r4.z + hw4.w * r4.w;
        }
        // 5-level batched butterfly: after level lev, A[i] holds value
        // index (i<<(lev+1)) | (lane & ((1<<(lev+1))-1)), partially summed.
        #pragma unroll
        for (int lev = 0; lev < 5; ++lev) {
            const int bit = (lane >> lev) & 1;
            #pragma unroll
            for (int i = 0; i < (32 >> 1); ++i) {
                if (i < (32 >> (lev + 1))) {
                    const float keep = bit ? A[2 * i + 1] : A[2 * i];
                    const float send = bit ? A[2 * i]     : A[2 * i + 1];
                    A[i] = keep + __shfl_xor(send, 1 << lev, 64);
                }
            }
        }
        sc[h] = A[0] + __shfl_xor(A[0], 32, 64);   // full sum over 64 lanes
    }

    // ---- masked softmax, fully in-wave: lane l owns m = l ----
    {
        // mask dtype detection: int32 0/1 -> bytes at i%4!=0 are all zero
        const unsigned char v0 = mask_left[lane];
        const bool mask_u8 = (__ballot(((lane & 3) != 0) && (v0 != 0)) != 0ULL);

        float s = (lane >> 5) ? sc[1] : sc[0];
        const bool msk = mask_u8
            ? (mask[(size_t)b * MM + lane] != 0)
            : (((const int*)(const void*)mask)[(size_t)b * MM + lane] != 0);
        if (msk) s = -__builtin_inff();
        float mx = s;
        #pragma unroll
        for (int off = 32; off >= 1; off >>= 1) mx = fmaxf(mx, __shfl_xor(mx, off, 64));
        const float e = __expf(s - mx);
        float sum = e;
        #pragma unroll
        for (int off = 32; off >= 1; off >>= 1) sum += __shfl_xor(sum, off, 64);
        att_s[pair][lane] = e / sum;               // same wave reads below, no barrier
    }

    // ---- ctx[d] = sum_m att[m] * tail[b,m,d] ; LDS broadcast reads ----
    float4 acc = make_float4(0.f, 0.f, 0.f, 0.f);
    #pragma unroll 8
    for (int m = 0; m < MM; ++m) {
        const float a = att_s[pair][m];
        const float4 v = *(const float4*)(tail + ((size_t)(b * MM + m)) * DD + 4 * lane);
        acc.x += a * v.x; acc.y += a * v.y; acc.z += a * v.z; acc.w += a * v.w;
    }
    *(float4*)(ctx + (size_t)(side * NB + b) * DD + 4 * lane) = acc;
}

// ---------------- E: out = LN(relu([ctx|head] @ wcat) + head) ----------------
__global__ __launch_bounds__(512)
void k_outln(const float* __restrict__ ctx,
             const float* __restrict__ head_left,
             const float* __restrict__ head_right,
             const float* __restrict__ wcat,
             const float* __restrict__ gamma,
             const float* __restrict__ beta,
             float* __restrict__ out)
{
    const int blk  = blockIdx.x;           // 512 blocks x 16 rows
    const int t    = threadIdx.x;          // 512 threads, 8 waves
    const int lane = t & 63;
    const int w    = t >> 6;

    __shared__ float x_s[16][512];         // [r][0:256)=ctx, [256:512)=head_side

    const int  side = (blk * 16) >> 12;    // uniform per block
    const float* __restrict__ head = side ? head_right : head_left;

    // cooperative load: 16*512 floats / 512 threads = 16 each, coalesced
    #pragma unroll
    for (int i = 0; i < 16; ++i) {
        const int idx = i * 512 + t;
        const int r   = idx >> 9;
        const int c   = idx & 511;
        const int rg  = blk * 16 + r;
        const int bb  = rg & (NB - 1);
        x_s[r][c] = (c < DD) ? ctx[(size_t)rg * DD + c]
                             : head[(size_t)bb * DD + (c - DD)];
    }
    __syncthreads();

    float4 acc[2];
    acc[0] = make_float4(0.f, 0.f, 0.f, 0.f);
    acc[1] = make_float4(0.f, 0.f, 0.f, 0.f);

    #pragma unroll 4
    for (int k = 0; k < 512; ++k) {
        const float4 w4 = *(const float4*)(wcat + (size_t)k * DD + 4 * lane);
        #pragma unroll
        for (int r = 0; r < 2; ++r) {
            const float x = x_s[2 * w + r][k];
            acc[r].x += x * w4.x; acc[r].y += x * w4.y;
            acc[r].z += x * w4.z; acc[r].w += x * w4.w;
        }
    }

    const float4 g4 = *(const float4*)(gamma + 4 * lane);
    const float4 b4 = *(const float4*)(beta  + 4 * lane);

    #pragma unroll
    for (int r = 0; r < 2; ++r) {
        const int rl = 2 * w + r;
        const float4 h4 = *(const float4*)(&x_s[rl][DD + 4 * lane]);
        float4 y;
        y.x = fmaxf(acc[r].x, 0.f) + h4.x;
        y.y = fmaxf(acc[r].y, 0.f) + h4.y;
        y.z = fmaxf(acc[r].z, 0.f) + h4.z;
        y.w = fmaxf(acc[r].w, 0.f) + h4.w;

        float s1 = y.x + y.y + y.z + y.w;
        float s2 = y.x * y.x + y.y * y.y + y.z * y.z + y.w * y.w;
        #pragma unroll
        for (int off = 32; off >= 1; off >>= 1) {
            s1 += __shfl_xor(s1, off, 64);
            s2 += __shfl_xor(s2, off, 64);
        }
        const float mu   = s1 * (1.0f / DD);
        const float var  = s2 * (1.0f / DD) - mu * mu;
        const float rstd = rsqrtf(var + LN_EPS);

        float4 o;
        o.x = (y.x - mu) * rstd * g4.x + b4.x;
        o.y = (y.y - mu) * rstd * g4.y + b4.y;
        o.z = (y.z - mu) * rstd * g4.z + b4.z;
        o.w = (y.w - mu) * rstd * g4.w + b4.w;
        *(float4*)(out + (size_t)(blk * 16 + rl) * DD + 4 * lane) = o;
    }
}

extern "C" void kernel_launch(void* const* d_in, const int* in_sizes, int n_in,
                              void* d_out, int out_size, void* d_ws, size_t ws_size,
                              hipStream_t stream) {
    const float* head_left  = (const float*)d_in[0];
    const float* rel_left   = (const float*)d_in[1];
    const float* tail_left  = (const float*)d_in[2];
    const float* head_right = (const float*)d_in[3];
    const float* rel_right  = (const float*)d_in[4];
    const float* tail_right = (const float*)d_in[5];
    const unsigned char* mask_left  = (const unsigned char*)d_in[6];
    const unsigned char* mask_right = (const unsigned char*)d_in[7];
    const float* bw    = (const float*)d_in[8];
    const float* wt    = (const float*)d_in[9];
    const float* wh    = (const float*)d_in[10];
    const float* gamma = (const float*)d_in[11];
    const float* beta  = (const float*)d_in[12];
    float* out = (float*)d_out;

    float* ws   = (float*)d_ws;
    float* wcat = ws + WS_WCAT;
    float* hW   = ws + WS_HW;
    float* ctx  = ws + WS_CTX;

    k_transpose<<<dim3(32),   dim3(256), 0, stream>>>(wt, wh, wcat);
    k_bilinear <<<dim3(256),  dim3(256), 0, stream>>>(head_left, head_right, bw, hW);
    k_attn     <<<dim3(2048), dim3(256), 0, stream>>>(rel_left, tail_left, rel_right, tail_right,
                                                      mask_left, mask_right, hW, ctx);
    k_outln    <<<dim3(512),  dim3(512), 0, stream>>>(ctx, head_left, head_right, wcat,
                                                      gamma, beta, out);
}

// Round 4
// 305.940 us; speedup vs baseline: 1.0441x; 1.0441x over previous
//
#include <hip/hip_runtime.h>

#define NB 4096
#define MM 64
#define DD 256
#define LN_EPS 1e-5f
#define NEG_BIG -1e30f

// ws layout (floats):
//   [0,            512*DD)    wcat : [wt^T ; wh^T]
//   [WS_HW,  +NB*DD)          hW
//   [WS_CTX, +2*NB*DD)        ctx  (row = side*NB + b)
#define WS_WCAT 0
#define WS_HW   (512 * DD)
#define WS_CTX  (WS_HW + NB * DD)

// ---------------- prep: blocks 0..31 transpose wt/wh, 32..287 bilinear ----------------
__global__ __launch_bounds__(256)
void k_prep(const float* __restrict__ head_left,
            const float* __restrict__ head_right,
            const float* __restrict__ bw,
            const float* __restrict__ wt,
            const float* __restrict__ wh,
            float* __restrict__ wcat,
            float* __restrict__ hW)
{
    __shared__ float smem[64 * 65];      // transpose tile OR weak_s[16][256]
    const int t = threadIdx.x;

    if (blockIdx.x < 32) {
        const int mat   = blockIdx.x >> 4;
        const int tile  = blockIdx.x & 15;
        const int dBase = (tile >> 2) * 64;
        const int kBase = (tile & 3) * 64;
        const float* __restrict__ w = mat ? wh : wt;
        float (*tile_s)[65] = (float(*)[65])smem;
        const int c  = t & 63;
        const int rr = t >> 6;
        #pragma unroll
        for (int r = rr; r < 64; r += 4)
            tile_s[r][c] = w[(dBase + r) * DD + kBase + c];
        __syncthreads();
        #pragma unroll
        for (int kr = rr; kr < 64; kr += 4)
            wcat[(mat * 256 + kBase + kr) * DD + dBase + c] = tile_s[c][kr];
    } else {
        const int blk  = blockIdx.x - 32;     // 256 blocks x 16 rows
        const int lane = t & 63;
        const int w    = t >> 6;
        float (*weak_s)[DD] = (float(*)[DD])smem;
        #pragma unroll
        for (int r = 0; r < 16; ++r) {
            const size_t idx = (size_t)(blk * 16 + r) * DD + t;
            weak_s[r][t] = head_right[idx] - head_left[idx];
        }
        __syncthreads();

        float4 acc[4];
        #pragma unroll
        for (int r = 0; r < 4; ++r) acc[r] = make_float4(0.f, 0.f, 0.f, 0.f);
        for (int k = 0; k < DD; ++k) {
            const float4 w4 = *(const float4*)(bw + k * DD + 4 * lane);
            #pragma unroll
            for (int r = 0; r < 4; ++r) {
                const float x = weak_s[4 * w + r][k];
                acc[r].x += x * w4.x; acc[r].y += x * w4.y;
                acc[r].z += x * w4.z; acc[r].w += x * w4.w;
            }
        }
        #pragma unroll
        for (int r = 0; r < 4; ++r)
            *(float4*)(hW + (size_t)(blk * 16 + 4 * w + r) * DD + 4 * lane) = acc[r];
    }
}

// ---------------- attn: flash-style, rel+tail streams interleaved ----------------
// Block = 1 (b,side) pair, 4 waves; wave owns 16 rows = 2 chunks of 8.
// Per chunk: load 8 rel + 8 tail rows together; online softmax keeps
// (m_run, denom, ctx_acc) per wave; one barrier + cross-wave combine.
__global__ __launch_bounds__(256, 5)
void k_attn(const float* __restrict__ rel_left,
            const float* __restrict__ tail_left,
            const float* __restrict__ rel_right,
            const float* __restrict__ tail_right,
            const unsigned char* __restrict__ mask_left,
            const unsigned char* __restrict__ mask_right,
            const float* __restrict__ hW,
            float* __restrict__ ctx)
{
    const int t    = threadIdx.x;
    const int lane = t & 63;
    const int w    = t >> 6;
    const int b    = blockIdx.x >> 1;
    const int side = blockIdx.x & 1;

    const float* __restrict__ rel  = side ? rel_right  : rel_left;
    const float* __restrict__ tail = side ? tail_right : tail_left;
    const unsigned char* __restrict__ mask = side ? mask_right : mask_left;

    __shared__ float part_s[4][DD];
    __shared__ float m_s[4], d_s[4];

    const float4 hw4 = *(const float4*)(hW + (size_t)b * DD + 4 * lane);

    // mask dtype detection: int32 0/1 -> all bytes at i%4!=0 are zero
    const unsigned char v0 = mask_left[lane];
    const bool mask_u8 = (__ballot(((lane & 3) != 0) && (v0 != 0)) != 0ULL);

    float4 acc = make_float4(0.f, 0.f, 0.f, 0.f);
    float m_run = NEG_BIG, denom = 0.f;

    const int row0 = w * 16;
    #pragma unroll 1
    for (int c = 0; c < 2; ++c) {
        const int base = row0 + c * 8;
        const float* rp = rel  + ((size_t)(b * MM + base)) * DD + 4 * lane;
        const float* tp = tail + ((size_t)(b * MM + base)) * DD + 4 * lane;

        float4 R[8], T[8];
        #pragma unroll
        for (int j = 0; j < 8; ++j) R[j] = *(const float4*)(rp + j * DD);
        #pragma unroll
        for (int j = 0; j < 8; ++j) T[j] = *(const float4*)(tp + j * DD);

        // per-lane partial dots for the 8 rows
        float A[8];
        #pragma unroll
        for (int j = 0; j < 8; ++j)
            A[j] = hw4.x * R[j].x + hw4.y * R[j].y + hw4.z * R[j].z + hw4.w * R[j].w;

        // batched butterfly: 3 levels -> A[0] = row (lane&7) partial across stride-8 groups
        #pragma unroll
        for (int lev = 0; lev < 3; ++lev) {
            const int bit = (lane >> lev) & 1;
            #pragma unroll
            for (int i = 0; i < 4; ++i) {
                if (i < (8 >> (lev + 1))) {
                    const float keep = bit ? A[2 * i + 1] : A[2 * i];
                    const float send = bit ? A[2 * i]     : A[2 * i + 1];
                    A[i] = keep + __shfl_xor(send, 1 << lev, 64);
                }
            }
        }
        float s = A[0];
        s += __shfl_xor(s, 8, 64);
        s += __shfl_xor(s, 16, 64);
        s += __shfl_xor(s, 32, 64);      // lane l now holds full score of row base+(l&7)

        const int mrow = base + (lane & 7);
        const bool msk = mask_u8
            ? (mask[(size_t)b * MM + mrow] != 0)
            : (((const int*)(const void*)mask)[(size_t)b * MM + mrow] != 0);
        if (msk) s = NEG_BIG;            // -1e30: all-masked chunks self-heal via rescale

        float cmax = s;
        cmax = fmaxf(cmax, __shfl_xor(cmax, 1, 64));
        cmax = fmaxf(cmax, __shfl_xor(cmax, 2, 64));
        cmax = fmaxf(cmax, __shfl_xor(cmax, 4, 64));

        const float m_new = fmaxf(m_run, cmax);
        const float r = __expf(m_run - m_new);
        const float p = __expf(s - m_new);
        float psum = p;
        psum += __shfl_xor(psum, 1, 64);
        psum += __shfl_xor(psum, 2, 64);
        psum += __shfl_xor(psum, 4, 64);
        denom = denom * r + psum;
        m_run = m_new;
        acc.x *= r; acc.y *= r; acc.z *= r; acc.w *= r;

        #pragma unroll
        for (int j = 0; j < 8; ++j) {
            const float aj = __shfl(p, j, 64);   // lane j holds row base+j's weight
            acc.x += aj * T[j].x; acc.y += aj * T[j].y;
            acc.z += aj * T[j].z; acc.w += aj * T[j].w;
        }
    }

    *(float4*)(&part_s[w][4 * lane]) = acc;
    if (lane == 0) { m_s[w] = m_run; d_s[w] = denom; }
    __syncthreads();

    // cross-wave combine (safe: fully-masked waves get weight exp(-1e30-M)=0)
    const float M  = fmaxf(fmaxf(m_s[0], m_s[1]), fmaxf(m_s[2], m_s[3]));
    const float e0 = __expf(m_s[0] - M), e1 = __expf(m_s[1] - M);
    const float e2 = __expf(m_s[2] - M), e3 = __expf(m_s[3] - M);
    const float den = d_s[0] * e0 + d_s[1] * e1 + d_s[2] * e2 + d_s[3] * e3;
    const float num = part_s[0][t] * e0 + part_s[1][t] * e1
                    + part_s[2][t] * e2 + part_s[3][t] * e3;
    ctx[(size_t)(side * NB + b) * DD + t] = num / den;
}

// ---------------- E: out = LN(relu([ctx|head] @ wcat) + head) ----------------
__global__ __launch_bounds__(512)
void k_outln(const float* __restrict__ ctx,
             const float* __restrict__ head_left,
             const float* __restrict__ head_right,
             const float* __restrict__ wcat,
             const float* __restrict__ gamma,
             const float* __restrict__ beta,
             float* __restrict__ out)
{
    const int blk  = blockIdx.x;           // 512 blocks x 16 rows
    const int t    = threadIdx.x;          // 512 threads, 8 waves
    const int lane = t & 63;
    const int w    = t >> 6;

    __shared__ float x_s[16][512];

    const int  side = (blk * 16) >> 12;
    const float* __restrict__ head = side ? head_right : head_left;

    #pragma unroll
    for (int i = 0; i < 16; ++i) {
        const int idx = i * 512 + t;
        const int r   = idx >> 9;
        const int c   = idx & 511;
        const int rg  = blk * 16 + r;
        const int bb  = rg & (NB - 1);
        x_s[r][c] = (c < DD) ? ctx[(size_t)rg * DD + c]
                             : head[(size_t)bb * DD + (c - DD)];
    }
    __syncthreads();

    float4 acc[2];
    acc[0] = make_float4(0.f, 0.f, 0.f, 0.f);
    acc[1] = make_float4(0.f, 0.f, 0.f, 0.f);

    #pragma unroll 4
    for (int k = 0; k < 512; ++k) {
        const float4 w4 = *(const float4*)(wcat + (size_t)k * DD + 4 * lane);
        #pragma unroll
        for (int r = 0; r < 2; ++r) {
            const float x = x_s[2 * w + r][k];
            acc[r].x += x * w4.x; acc[r].y += x * w4.y;
            acc[r].z += x * w4.z; acc[r].w += x * w4.w;
        }
    }

    const float4 g4 = *(const float4*)(gamma + 4 * lane);
    const float4 b4 = *(const float4*)(beta  + 4 * lane);

    #pragma unroll
    for (int r = 0; r < 2; ++r) {
        const int rl = 2 * w + r;
        const float4 h4 = *(const float4*)(&x_s[rl][DD + 4 * lane]);
        float4 y;
        y.x = fmaxf(acc[r].x, 0.f) + h4.x;
        y.y = fmaxf(acc[r].y, 0.f) + h4.y;
        y.z = fmaxf(acc[r].z, 0.f) + h4.z;
        y.w = fmaxf(acc[r].w, 0.f) + h4.w;

        float s1 = y.x + y.y + y.z + y.w;
        float s2 = y.x * y.x + y.y * y.y + y.z * y.z + y.w * y.w;
        #pragma unroll
        for (int off = 32; off >= 1; off >>= 1) {
            s1 += __shfl_xor(s1, off, 64);
            s2 += __shfl_xor(s2, off, 64);
        }
        const float mu   = s1 * (1.0f / DD);
        const float var  = s2 * (1.0f / DD) - mu * mu;
        const float rstd = rsqrtf(var + LN_EPS);

        float4 o;
        o.x = (y.x - mu) * rstd * g4.x + b4.x;
        o.y = (y.y - mu) * rstd * g4.y + b4.y;
        o.z = (y.z - mu) * rstd * g4.z + b4.z;
        o.w = (y.w - mu) * rstd * g4.w + b4.w;
        *(float4*)(out + (size_t)(blk * 16 + rl) * DD + 4 * lane) = o;
    }
}

extern "C" void kernel_launch(void* const* d_in, const int* in_sizes, int n_in,
                              void* d_out, int out_size, void* d_ws, size_t ws_size,
                              hipStream_t stream) {
    const float* head_left  = (const float*)d_in[0];
    const float* rel_left   = (const float*)d_in[1];
    const float* tail_left  = (const float*)d_in[2];
    const float* head_right = (const float*)d_in[3];
    const float* rel_right  = (const float*)d_in[4];
    const float* tail_right = (const float*)d_in[5];
    const unsigned char* mask_left  = (const unsigned char*)d_in[6];
    const unsigned char* mask_right = (const unsigned char*)d_in[7];
    const float* bw    = (const float*)d_in[8];
    const float* wt    = (const float*)d_in[9];
    const float* wh    = (const float*)d_in[10];
    const float* gamma = (const float*)d_in[11];
    const float* beta  = (const float*)d_in[12];
    float* out = (float*)d_out;

    float* ws   = (float*)d_ws;
    float* wcat = ws + WS_WCAT;
    float* hW   = ws + WS_HW;
    float* ctx  = ws + WS_CTX;

    k_prep <<<dim3(288),  dim3(256), 0, stream>>>(head_left, head_right, bw, wt, wh, wcat, hW);
    k_attn <<<dim3(8192), dim3(256), 0, stream>>>(rel_left, tail_left, rel_right, tail_right,
                                                  mask_left, mask_right, hW, ctx);
    k_outln<<<dim3(512),  dim3(512), 0, stream>>>(ctx, head_left, head_right, wcat,
                                                  gamma, beta, out);
}